// Round 6
// baseline (618.269 us; speedup 1.0000x reference)
//
#include <hip/hip_runtime.h>
#include <hip/hip_bf16.h>

#define T_TOKENS 4096
#define D_MODEL  1024
#define N_EXP    16
#define D_FF     1024
#define D_FF_SH  2048

typedef __attribute__((ext_vector_type(8))) short short8;
typedef __attribute__((ext_vector_type(4))) float float4v;

__device__ __forceinline__ short f2bf(float f) {
    union { float f; unsigned u; } c; c.f = f;
    unsigned u = c.u + 0x7fffu + ((c.u >> 16) & 1u);
    return (short)(u >> 16);
}

// async global->LDS, 16B per lane; LDS dest = wave-uniform base + lane*16.
__device__ __forceinline__ void gload16(const void* g, void* l) {
    __builtin_amdgcn_global_load_lds(
        (const __attribute__((address_space(1))) void*)g,
        (__attribute__((address_space(3))) void*)l, 16, 0, 0);
}

// ---------------------------------------------------------------- convert (all 4 weights, one dispatch)
__global__ __launch_bounds__(256) void convert_all_kernel(
    const float* __restrict__ s0, short* __restrict__ d0,   // egu   33554432
    const float* __restrict__ s1, short* __restrict__ d1,   // edown 16777216
    const float* __restrict__ s2, short* __restrict__ d2,   // sgu    4194304
    const float* __restrict__ s3, short* __restrict__ d3) { // sdown  2097152
    int c = blockIdx.x * 256 + threadIdx.x;   // chunk of 8 elements
    const float* s; short* d; int off;
    if      (c < 4194304) { s = s0; d = d0; off = c; }
    else if (c < 6291456) { s = s1; d = d1; off = c - 4194304; }
    else if (c < 6815744) { s = s2; d = d2; off = c - 6291456; }
    else                  { s = s3; d = d3; off = c - 6815744; }
    size_t i = (size_t)off * 8;
    float4 a = *(const float4*)(s + i);
    float4 b = *(const float4*)(s + i + 4);
    union { short sh[8]; int4 v; } p;
    p.sh[0] = f2bf(a.x); p.sh[1] = f2bf(a.y); p.sh[2] = f2bf(a.z); p.sh[3] = f2bf(a.w);
    p.sh[4] = f2bf(b.x); p.sh[5] = f2bf(b.y); p.sh[6] = f2bf(b.z); p.sh[7] = f2bf(b.w);
    *(int4*)(d + i) = p.v;
}

// ---------------------------------------------------------------- router (fp32 exact, LDS-staged weights)
__global__ __launch_bounds__(256) void router_kernel(
    const float* __restrict__ x, const float* __restrict__ gw, const float* __restrict__ sgw,
    short* __restrict__ xb, int* __restrict__ topk_id, float* __restrict__ topk_w,
    float* __restrict__ gate, int* __restrict__ counts) {
    __shared__ float gwl[17 * 1024];   // 69632 B
    int tid = threadIdx.x;
#pragma unroll
    for (int i = 0; i < 16; i++)
        *(float4*)&gwl[tid * 4 + i * 1024] = *(const float4*)&gw[tid * 4 + i * 1024];
    *(float4*)&gwl[16384 + tid * 4] = *(const float4*)&sgw[tid * 4];
    __syncthreads();

    int wave = tid >> 6, lane = tid & 63;
    int t0 = blockIdx.x * 16 + wave * 4;

    float acc[4][17];
#pragma unroll
    for (int tt = 0; tt < 4; tt++)
#pragma unroll
        for (int e = 0; e < 17; e++) acc[tt][e] = 0.f;

#pragma unroll
    for (int i = 0; i < 4; i++) {
        int d = lane * 4 + i * 256;
        float4 xv[4];
#pragma unroll
        for (int tt = 0; tt < 4; tt++) {
            xv[tt] = *(const float4*)&x[(size_t)(t0 + tt) * D_MODEL + d];
            union { short sh[4]; int2 v; } p;
            p.sh[0] = f2bf(xv[tt].x); p.sh[1] = f2bf(xv[tt].y);
            p.sh[2] = f2bf(xv[tt].z); p.sh[3] = f2bf(xv[tt].w);
            *(int2*)&xb[(size_t)(t0 + tt) * D_MODEL + d] = p.v;
        }
#pragma unroll
        for (int e = 0; e < 17; e++) {
            float4 g = *(const float4*)&gwl[e * 1024 + d];
#pragma unroll
            for (int tt = 0; tt < 4; tt++)
                acc[tt][e] += xv[tt].x * g.x + xv[tt].y * g.y + xv[tt].z * g.z + xv[tt].w * g.w;
        }
    }

#pragma unroll
    for (int tt = 0; tt < 4; tt++)
#pragma unroll
        for (int e = 0; e < 17; e++)
            for (int off = 32; off; off >>= 1) acc[tt][e] += __shfl_xor(acc[tt][e], off);

    if (lane == 0) {
#pragma unroll
        for (int tt = 0; tt < 4; tt++) {
            int t = t0 + tt;
            float v1 = -1e30f, v2 = -1e30f; int i1 = 0, i2 = 0;
#pragma unroll
            for (int e = 0; e < 16; e++) {
                float v = acc[tt][e];
                if (v > v1) { v2 = v1; i2 = i1; v1 = v; i1 = e; }
                else if (v > v2) { v2 = v; i2 = e; }
            }
            float e2 = expf(v2 - v1);
            float s = 1.f + e2;
            topk_id[t * 2] = i1; topk_id[t * 2 + 1] = i2;
            topk_w[t * 2] = 1.f / s; topk_w[t * 2 + 1] = e2 / s;
            gate[t] = 1.f / (1.f + expf(-acc[tt][16]));
            atomicAdd(&counts[i1], 1); atomicAdd(&counts[i2], 1);
        }
    }
}

// ---------------------------------------------------------------- offsets + live 256-row-tile map
__global__ void offsets_kernel(const int* __restrict__ counts, int* __restrict__ offsets,
                               int* __restrict__ cursor, int* __restrict__ tile_map,
                               int* __restrict__ n_tiles) {
    if (threadIdx.x == 0) {
        int off = 0, nt = 0;
        for (int e = 0; e < N_EXP; e++) {
            offsets[e] = off; cursor[e] = off;
            int c = counts[e];
            for (int r = 0; r < c; r += 256) tile_map[nt++] = (e << 16) | (r >> 8);
            off += c;
        }
        n_tiles[0] = nt;
    }
}

__global__ __launch_bounds__(256) void scatter_kernel(
    const int* __restrict__ topk_id, const float* __restrict__ topk_w,
    int* __restrict__ cursor, int* __restrict__ tok_list, float* __restrict__ tok_w,
    int* __restrict__ slot_of) {
    int t = blockIdx.x * 256 + threadIdx.x;
#pragma unroll
    for (int k = 0; k < 2; k++) {
        int e = topk_id[t * 2 + k];
        int pos = atomicAdd(&cursor[e], 1);
        tok_list[pos] = t;
        tok_w[pos] = topk_w[t * 2 + k];
        slot_of[t * 2 + k] = pos;
    }
}

// ---------------------------------------------------------------- GEMM1: 256x128 tile, persistent work list
// items: [0, nt*8) expert (tile=it>>3, col=(it&7)*128); [nt*8, nt*8+256) shared (row=(s>>4)*256, col=(s&15)*128)
__global__ __launch_bounds__(512, 2) void gemm1_kernel(
    const short* __restrict__ xb,
    const short* __restrict__ Wexp,   // [16][2048][1024]
    const short* __restrict__ Wsh,    // [4096][1024]
    short* __restrict__ Hexp,         // [8192][1024]
    short* __restrict__ Hsh,          // [4096][2048]
    const int* __restrict__ tok_list,
    const int* __restrict__ offsets, const int* __restrict__ counts,
    const int* __restrict__ tile_map, const int* __restrict__ n_tiles) {
    __shared__ char lds[65536];

    int nt = n_tiles[0];
    int total = nt * 8 + 256;

    int t = threadIdx.x;
    int wave = t >> 6, lane = t & 63;
    int wm = (wave & 3) * 64, wn = (wave >> 2) * 64;
    int fr = lane & 15, fk2 = (lane >> 4) * 16;
    int rA = t >> 2;              // 0..127
    int cq = (t & 3) * 8;         // shorts
    int lo = t * 16;
    int erow = (lane >> 4) * 4;
    int ecol = lane & 15;

    for (int it = blockIdx.x; it < total; it += gridDim.x) {
        int count, row0, col0, dff;
        const int* idx = nullptr;
        const short* Wg; short* Hout;
        if (it < nt * 8) {
            int tm = tile_map[it >> 3];
            int e = tm >> 16; row0 = (tm & 0xffff) << 8;
            col0 = (it & 7) * 128;
            count = counts[e];
            int base = offsets[e];
            idx = tok_list + base;
            Wg = Wexp + (size_t)e * 2 * D_FF * D_MODEL;
            Hout = Hexp + (size_t)base * D_FF;
            dff = D_FF;
        } else {
            int s = it - nt * 8;
            row0 = (s >> 4) * 256; col0 = (s & 15) * 128;
            count = T_TOKENS;
            Wg = Wsh; Hout = Hsh; dff = D_FF_SH;
        }
        const short* Wu = Wg + (size_t)dff * D_MODEL;

        float4v accg[4][4], accu[4][4];
#pragma unroll
        for (int i = 0; i < 4; i++)
#pragma unroll
            for (int j = 0; j < 4; j++) { accg[i][j] = (float4v)0.f; accu[i][j] = (float4v)0.f; }

        int r0c = min(row0 + rA, count - 1);
        int r1c = min(row0 + rA + 128, count - 1);
        int g0 = idx ? idx[r0c] : r0c;
        int g1 = idx ? idx[r1c] : r1c;
        const short* aP0 = xb + (size_t)g0 * D_MODEL + cq;
        const short* aP1 = xb + (size_t)g1 * D_MODEL + cq;
        const short* bgP = Wg + (size_t)(col0 + rA) * D_MODEL + cq;
        const short* buP = Wu + (size_t)(col0 + rA) * D_MODEL + cq;

        __syncthreads();          // previous item's LDS reads must finish
        gload16(aP0, lds + lo);
        gload16(aP1, lds + 8192 + lo);
        gload16(bgP, lds + 16384 + lo);
        gload16(buP, lds + 24576 + lo);

        const int NK = D_MODEL / 32;  // 32 slices
        for (int k = 0; k < NK; k++) {
            __syncthreads();          // drains slice-k DMAs (overlapped by compute(k-1))
            if (k + 1 < NK) {
                int s = ((k + 1) & 1) * 32768;
                int off = (k + 1) * 32;
                gload16(aP0 + off, lds + s + lo);
                gload16(aP1 + off, lds + s + 8192 + lo);
                gload16(bgP + off, lds + s + 16384 + lo);
                gload16(buP + off, lds + s + 24576 + lo);
            }
            int sb = (k & 1) * 32768;
            short8 af[4], bgf[4], buf[4];
#pragma unroll
            for (int i = 0; i < 4; i++)
                af[i] = *(const short8*)(lds + sb + (wm + i * 16 + fr) * 64 + fk2);
#pragma unroll
            for (int j = 0; j < 4; j++) {
                bgf[j] = *(const short8*)(lds + sb + 16384 + (wn + j * 16 + fr) * 64 + fk2);
                buf[j] = *(const short8*)(lds + sb + 24576 + (wn + j * 16 + fr) * 64 + fk2);
            }
#pragma unroll
            for (int i = 0; i < 4; i++)
#pragma unroll
                for (int j = 0; j < 4; j++) {
                    accg[i][j] = __builtin_amdgcn_mfma_f32_16x16x32_bf16(af[i], bgf[j], accg[i][j], 0, 0, 0);
                    accu[i][j] = __builtin_amdgcn_mfma_f32_16x16x32_bf16(af[i], buf[j], accu[i][j], 0, 0, 0);
                }
        }

#pragma unroll
        for (int i = 0; i < 4; i++)
#pragma unroll
            for (int j = 0; j < 4; j++)
#pragma unroll
                for (int r = 0; r < 4; r++) {
                    int row = wm + i * 16 + erow + r;
                    if (row0 + row < count) {
                        float g = accg[i][j][r], u = accu[i][j][r];
                        float h = g / (1.f + expf(-g)) * u;
                        Hout[(size_t)(row0 + row) * dff + col0 + wn + j * 16 + ecol] = f2bf(h);
                    }
                }
    }
}

// ---------------------------------------------------------------- GEMM2: 256x128 tile, persistent work list
// items: [0, nt*8) expert; [nt*8, nt*8+128) shared (row=(s>>3)*256, col=(s&7)*128)
__global__ __launch_bounds__(512, 2) void gemm2_kernel(
    const short* __restrict__ Hexp, const short* __restrict__ Hsh,
    const short* __restrict__ Wdexp,  // [16][1024][1024]
    const short* __restrict__ Wdsh,   // [1024][2048]
    float* __restrict__ oslots,       // [8192][1024]
    float* __restrict__ out,          // [4096][1024]
    const float* __restrict__ tok_w, const float* __restrict__ gate,
    const int* __restrict__ offsets, const int* __restrict__ counts,
    const int* __restrict__ tile_map, const int* __restrict__ n_tiles) {
    __shared__ char lds[49152];   // 2 x 24KB slices (A16K|B8K)

    int nt = n_tiles[0];
    int total = nt * 8 + 128;

    int t = threadIdx.x;
    int wave = t >> 6, lane = t & 63;
    int wm = (wave & 3) * 64, wn = (wave >> 2) * 64;
    int fr = lane & 15, fk2 = (lane >> 4) * 16;
    int rA = t >> 2;
    int cq = (t & 3) * 8;
    int lo = t * 16;
    int erow = (lane >> 4) * 4;
    int ecol = lane & 15;

    for (int it = blockIdx.x; it < total; it += gridDim.x) {
        int count, row0, col0, K, base;
        const short* Ab; const short* B;
        bool shared_part;
        if (it < nt * 8) {
            int tm = tile_map[it >> 3];
            int e = tm >> 16; row0 = (tm & 0xffff) << 8;
            col0 = (it & 7) * 128;
            count = counts[e]; base = offsets[e];
            Ab = Hexp + (size_t)base * D_FF; K = D_FF;
            B = Wdexp + (size_t)e * D_MODEL * D_FF;
            shared_part = false;
        } else {
            int s = it - nt * 8;
            row0 = (s >> 3) * 256; col0 = (s & 7) * 128;
            count = T_TOKENS; base = 0;
            Ab = Hsh; K = D_FF_SH; B = Wdsh; shared_part = true;
        }

        float4v acc[4][4];
#pragma unroll
        for (int i = 0; i < 4; i++)
#pragma unroll
            for (int j = 0; j < 4; j++) acc[i][j] = (float4v)0.f;

        int r0c = min(row0 + rA, count - 1);
        int r1c = min(row0 + rA + 128, count - 1);
        const short* aP0 = Ab + (size_t)r0c * K + cq;
        const short* aP1 = Ab + (size_t)r1c * K + cq;
        const short* bP  = B + (size_t)(col0 + rA) * K + cq;

        __syncthreads();
        gload16(aP0, lds + lo);
        gload16(aP1, lds + 8192 + lo);
        gload16(bP,  lds + 16384 + lo);

        const int NK = K / 32;        // 32 or 64
        for (int k = 0; k < NK; k++) {
            __syncthreads();
            if (k + 1 < NK) {
                int s = ((k + 1) & 1) * 24576;
                int off = (k + 1) * 32;
                gload16(aP0 + off, lds + s + lo);
                gload16(aP1 + off, lds + s + 8192 + lo);
                gload16(bP + off,  lds + s + 16384 + lo);
            }
            int sb = (k & 1) * 24576;
            short8 af[4], bf[4];
#pragma unroll
            for (int i = 0; i < 4; i++)
                af[i] = *(const short8*)(lds + sb + (wm + i * 16 + fr) * 64 + fk2);
#pragma unroll
            for (int j = 0; j < 4; j++)
                bf[j] = *(const short8*)(lds + sb + 16384 + (wn + j * 16 + fr) * 64 + fk2);
#pragma unroll
            for (int i = 0; i < 4; i++)
#pragma unroll
                for (int j = 0; j < 4; j++)
                    acc[i][j] = __builtin_amdgcn_mfma_f32_16x16x32_bf16(af[i], bf[j], acc[i][j], 0, 0, 0);
        }

#pragma unroll
        for (int i = 0; i < 4; i++)
#pragma unroll
            for (int j = 0; j < 4; j++)
#pragma unroll
                for (int r = 0; r < 4; r++) {
                    int row = wm + i * 16 + erow + r;
                    if (row0 + row < count) {
                        float v = acc[i][j][r];
                        int col = col0 + wn + j * 16 + ecol;
                        if (!shared_part) {
                            int slot = base + row0 + row;
                            oslots[(size_t)slot * D_MODEL + col] = tok_w[slot] * v;
                        } else {
                            out[(size_t)(row0 + row) * D_MODEL + col] = gate[row0 + row] * v;
                        }
                    }
                }
    }
}

// ---------------------------------------------------------------- combine: out[t] += oslots[sA] + oslots[sB]
__global__ __launch_bounds__(256) void combine_kernel(
    float* __restrict__ out, const float* __restrict__ oslots,
    const int* __restrict__ slot_of) {
    int t = blockIdx.x;
    int sA = slot_of[t * 2], sB = slot_of[t * 2 + 1];
    int d = threadIdx.x * 4;
    float4 o = *(float4*)&out[(size_t)t * D_MODEL + d];
    float4 a = *(const float4*)&oslots[(size_t)sA * D_MODEL + d];
    float4 b = *(const float4*)&oslots[(size_t)sB * D_MODEL + d];
    o.x += a.x + b.x; o.y += a.y + b.y; o.z += a.z + b.z; o.w += a.w + b.w;
    *(float4*)&out[(size_t)t * D_MODEL + d] = o;
}

// ---------------------------------------------------------------- host
extern "C" void kernel_launch(void* const* d_in, const int* in_sizes, int n_in,
                              void* d_out, int out_size, void* d_ws, size_t ws_size,
                              hipStream_t stream) {
    const float* x     = (const float*)d_in[0];
    const float* gw    = (const float*)d_in[1];
    const float* egu   = (const float*)d_in[2];
    const float* edown = (const float*)d_in[3];
    const float* sgu   = (const float*)d_in[4];
    const float* sdown = (const float*)d_in[5];
    const float* sgate = (const float*)d_in[6];
    float* out = (float*)d_out;
    char* ws = (char*)d_ws;

    const size_t XB_OFF     = 0;
    const size_t WGU_OFF    = XB_OFF     + (size_t)4096*1024*2;
    const size_t WDOWN_OFF  = WGU_OFF    + (size_t)16*2048*1024*2;
    const size_t WSGU_OFF   = WDOWN_OFF  + (size_t)16*1024*1024*2;
    const size_t WSDOWN_OFF = WSGU_OFF   + (size_t)4096*1024*2;
    const size_t HEXP_OFF   = WSDOWN_OFF + (size_t)1024*2048*2;
    const size_t HSH_OFF    = HEXP_OFF   + (size_t)8192*1024*2;
    const size_t OSLOT_OFF  = HSH_OFF    + (size_t)4096*2048*2;
    const size_t TID_OFF    = OSLOT_OFF  + (size_t)8192*1024*4;
    const size_t TW_OFF     = TID_OFF    + 4096*2*4;
    const size_t GATE_OFF   = TW_OFF     + 4096*2*4;
    const size_t TOKL_OFF   = GATE_OFF   + 4096*4;
    const size_t TOKW_OFF   = TOKL_OFF   + 8192*4;
    const size_t SLOT_OFF   = TOKW_OFF   + 8192*4;
    const size_t CNT_OFF    = SLOT_OFF   + 8192*4;
    const size_t OFFS_OFF   = CNT_OFF    + 256;
    const size_t CUR_OFF    = OFFS_OFF   + 256;
    const size_t TMAP_OFF   = CUR_OFF    + 256;
    const size_t NT_OFF     = TMAP_OFF   + 512;

    short* xb      = (short*)(ws + XB_OFF);
    short* wgu_b   = (short*)(ws + WGU_OFF);
    short* wdown_b = (short*)(ws + WDOWN_OFF);
    short* wsgu_b  = (short*)(ws + WSGU_OFF);
    short* wsdn_b  = (short*)(ws + WSDOWN_OFF);
    short* h_exp   = (short*)(ws + HEXP_OFF);
    short* h_sh    = (short*)(ws + HSH_OFF);
    float* oslots  = (float*)(ws + OSLOT_OFF);
    int*   topk_id = (int*)(ws + TID_OFF);
    float* topk_w  = (float*)(ws + TW_OFF);
    float* gate    = (float*)(ws + GATE_OFF);
    int*   tok_l   = (int*)(ws + TOKL_OFF);
    float* tok_w   = (float*)(ws + TOKW_OFF);
    int*   slot_of = (int*)(ws + SLOT_OFF);
    int*   counts  = (int*)(ws + CNT_OFF);
    int*   offsets = (int*)(ws + OFFS_OFF);
    int*   cursor  = (int*)(ws + CUR_OFF);
    int*   tmap    = (int*)(ws + TMAP_OFF);
    int*   ntiles  = (int*)(ws + NT_OFF);

    hipMemsetAsync(counts, 0, 64, stream);

    convert_all_kernel<<<27648, 256, 0, stream>>>(egu, wgu_b, edown, wdown_b,
                                                  sgu, wsgu_b, sdown, wsdn_b);
    router_kernel<<<256, 256, 0, stream>>>(x, gw, sgate, xb, topk_id, topk_w, gate, counts);
    offsets_kernel<<<1, 64, 0, stream>>>(counts, offsets, cursor, tmap, ntiles);
    scatter_kernel<<<T_TOKENS / 256, 256, 0, stream>>>(topk_id, topk_w, cursor, tok_l, tok_w, slot_of);

    // persistent compact grids: ~512 live items for gemm1, ~384 for gemm2
    gemm1_kernel<<<512, 512, 0, stream>>>(
        xb, wgu_b, wsgu_b, h_exp, h_sh, tok_l, offsets, counts, tmap, ntiles);

    gemm2_kernel<<<384, 512, 0, stream>>>(
        h_exp, h_sh, wdown_b, wsdn_b, oslots, out, tok_w, gate, offsets, counts, tmap, ntiles);

    combine_kernel<<<T_TOKENS, 256, 0, stream>>>(out, oslots, slot_of);
}